// Round 7
// baseline (113.965 us; speedup 1.0000x reference)
//
#include <hip/hip_runtime.h>

#define PCEN_EPS 1e-6f

// native clang vector type — required by __builtin_nontemporal_store
typedef float f32x4 __attribute__((ext_vector_type(4)));

// HW transcendentals (v_log_f32 = log2, v_exp_f32 = 2^x, v_sqrt_f32).
// NOTE: do NOT use __log2f/__exp2f — they collide with glibc math.h
// internal decls (__MATH_PRECNAME expansion) and break compilation.
#define HW_LOG2(x) __builtin_amdgcn_logf(x)
#define HW_EXP2(x) __builtin_amdgcn_exp2f(x)
#define HW_SQRT(x) __builtin_amdgcn_sqrtf(x)

// One WAVE per (b,c) row, lane-interleaved float4 layout (iteration k, lane i
// covers elements k*256 + 4*i..+3): every wave load/store is a contiguous,
// fully-utilized 1 KB burst.  Uniform-coefficient affine scan per 256-elem
// block, carry chained across iterations by one lane-63 broadcast + fma.
// smooth[0]=x[0] via carry-init = x[0] (a + s == 1).
//
// VALU-bound per round-5 counters (76us VALU vs 88.8us dur), so this rev:
//  - hardware log2/exp2 1:1 (no ln2 fixup muls): (sm+eps)^-a = 2^(-a*log2(sm+eps))
//  - r==0.5 wave-uniform fast path: (.)^0.5 via v_sqrt_f32 (1 trans vs 3)
//  - sq*e products hoisted (shared by affine pass and replay)
//  - predicate-free scan: fs = fmaf(m_d, shfl_up(fs,d), fs), m_d = lane>=d ? a4^d : 0
//  - temporal loads (x rides the 256MB L3 across replays), nontemporal stores
//  - 4-deep rotating register prefetch, static names
__global__ __launch_bounds__(256, 8) void pcen_kernel(
    const float* __restrict__ x,
    const float* __restrict__ alpha_p,
    const float* __restrict__ delta_p,
    const float* __restrict__ r_p,
    const float* __restrict__ s_p,
    float* __restrict__ out,
    int C)
{
    constexpr int T  = 8000;
    constexpr int NQ = T / 4;        // 2000 float4 per row

    const int wid  = threadIdx.x >> 6;            // wave in block: 0..3
    const int lane = threadIdx.x & 63;
    const int row  = blockIdx.x * 4 + wid;        // 0 .. B*C-1 (one wave/row)
    const int c    = row % C;

    // per-channel params (clipped like the reference) — wave-uniform
    const float alpha = fminf(fmaxf(alpha_p[c], 0.5f), 1.0f);
    const float delta = fminf(fmaxf(delta_p[c], 0.5f), 10.0f);
    const float r     = fminf(fmaxf(r_p[c],     0.1f), 1.0f);
    const float sq    = fminf(fmaxf(s_p[c],     0.001f), 0.5f);
    const float a     = 1.0f - sq;

    const float dr     = HW_EXP2(r * HW_LOG2(delta));   // delta^r
    const float nalpha = -alpha;

    // powers of a^4 for the uniform-coefficient scan
    const float a4  = (a * a) * (a * a);
    const float p1  = a4;
    const float p2  = p1 * p1;
    const float p4  = p2 * p2;
    const float p8  = p4 * p4;
    const float p16 = p8 * p8;
    const float p32 = p16 * p16;
    const float a256 = p32 * p32;
    const float inv_a4 = 1.0f / a4;

    // masked scan coefficients (lane-dependent, hoisted out of the loop)
    const float m1  = (lane >= 1)  ? p1  : 0.0f;
    const float m2  = (lane >= 2)  ? p2  : 0.0f;
    const float m4  = (lane >= 4)  ? p4  : 0.0f;
    const float m8  = (lane >= 8)  ? p8  : 0.0f;
    const float m16 = (lane >= 16) ? p16 : 0.0f;
    const float m32 = (lane >= 32) ? p32 : 0.0f;

    // Aexc = a4^lane (exclusive-prefix decay for this lane)
    float Aexc = 1.0f;
    if (lane & 1)  Aexc *= p1;
    if (lane & 2)  Aexc *= p2;
    if (lane & 4)  Aexc *= p4;
    if (lane & 8)  Aexc *= p8;
    if (lane & 16) Aexc *= p16;
    if (lane & 32) Aexc *= p32;

    const size_t base = (size_t)row * T;
    const f32x4* __restrict__ xin  = reinterpret_cast<const f32x4*>(x   + base);
    f32x4*       __restrict__ oout = reinterpret_cast<f32x4*>      (out + base);

    // carry init: sm[0] = a*carry + s*x[0] = x[0] when carry = x[0]
    float carry = x[base];

    // ---- 4-deep rotating prefetch pipeline (all prologue idx in range) ----
    int idx = lane;
    f32x4 e0 = xin[idx];
    f32x4 e1 = xin[idx +  64];
    f32x4 e2 = xin[idx + 128];
    f32x4 e3 = xin[idx + 192];

    // per-element tails: smv -> output value
#define PCEN_TAIL_POW(xv, smv, o_)                                           \
    {                                                                        \
        float t_ = HW_EXP2(nalpha * HW_LOG2((smv) + PCEN_EPS));              \
        o_ = HW_EXP2(r * HW_LOG2(fmaf((xv), t_, delta))) - dr;               \
    }
#define PCEN_TAIL_SQRT(xv, smv, o_)                                          \
    {                                                                        \
        float t_ = HW_EXP2(nalpha * HW_LOG2((smv) + PCEN_EPS));              \
        o_ = HW_SQRT(fmaf((xv), t_, delta)) - dr;                            \
    }

    // process one resident quad `eb` at `idx`, prefetch idx+256 into eb
#define PCEN_STEP(eb, TAIL)                                                  \
    {                                                                        \
        const int pidx = idx + 256;                                          \
        f32x4 pf = (f32x4)(0.f);                                             \
        if (pidx < NQ) pf = xin[pidx];                                       \
                                                                             \
        /* hoisted products, shared by affine pass and replay */             \
        const float gx = sq * eb.x, gy = sq * eb.y,                          \
                    gz = sq * eb.z, gw = sq * eb.w;                          \
                                                                             \
        float f = gx;                                                        \
        f = fmaf(a, f, gy);                                                  \
        f = fmaf(a, f, gz);                                                  \
        f = fmaf(a, f, gw);                                                  \
                                                                             \
        /* predicate-free uniform-coefficient scan */                        \
        float fs = f;                                                        \
        fs = fmaf(m1,  __shfl_up(fs, 1,  64), fs);                           \
        fs = fmaf(m2,  __shfl_up(fs, 2,  64), fs);                           \
        fs = fmaf(m4,  __shfl_up(fs, 4,  64), fs);                           \
        fs = fmaf(m8,  __shfl_up(fs, 8,  64), fs);                           \
        fs = fmaf(m16, __shfl_up(fs, 16, 64), fs);                           \
        fs = fmaf(m32, __shfl_up(fs, 32, 64), fs);                           \
                                                                             \
        float fe = (fs - f) * inv_a4;                                        \
        float sm = fmaf(Aexc, carry, fe);                                    \
                                                                             \
        float ftot = __shfl(fs, 63, 64);                                     \
        carry = fmaf(a256, carry, ftot);                                     \
                                                                             \
        f32x4 o;                                                             \
        sm = fmaf(a, sm, gx);  TAIL(eb.x, sm, o.x);                          \
        sm = fmaf(a, sm, gy);  TAIL(eb.y, sm, o.y);                          \
        sm = fmaf(a, sm, gz);  TAIL(eb.z, sm, o.z);                          \
        sm = fmaf(a, sm, gw);  TAIL(eb.w, sm, o.w);                          \
                                                                             \
        if (idx < NQ) __builtin_nontemporal_store(o, oout + idx);            \
        eb = pf;                                                             \
        idx += 64;                                                           \
    }

#define PCEN_MAIN_LOOP(TAIL)                                                 \
    _Pragma("unroll")                                                        \
    for (int k = 0; k < 8; ++k) {   /* 8 x 4 stages = 32 iterations */       \
        PCEN_STEP(e0, TAIL);                                                 \
        PCEN_STEP(e1, TAIL);                                                 \
        PCEN_STEP(e2, TAIL);                                                 \
        PCEN_STEP(e3, TAIL);                                                 \
    }

    if (r == 0.5f) {          // wave-uniform (r is channel-constant)
        PCEN_MAIN_LOOP(PCEN_TAIL_SQRT);
    } else {
        PCEN_MAIN_LOOP(PCEN_TAIL_POW);
    }

#undef PCEN_MAIN_LOOP
#undef PCEN_STEP
#undef PCEN_TAIL_POW
#undef PCEN_TAIL_SQRT
}

extern "C" void kernel_launch(void* const* d_in, const int* in_sizes, int n_in,
                              void* d_out, int out_size, void* d_ws, size_t ws_size,
                              hipStream_t stream) {
    const float* x     = (const float*)d_in[0];
    const float* alpha = (const float*)d_in[1];
    const float* delta = (const float*)d_in[2];
    const float* r     = (const float*)d_in[3];
    const float* s     = (const float*)d_in[4];
    float* out = (float*)d_out;

    const int T = 8000;                    // fixed by the reference problem
    const int C = in_sizes[1];             // 128
    const int rows = in_sizes[0] / T;      // B*C = 8192

    pcen_kernel<<<rows / 4, 256, 0, stream>>>(x, alpha, delta, r, s, out, C);
}

// Round 8
// 113.516 us; speedup vs baseline: 1.0040x; 1.0040x over previous
//
#include <hip/hip_runtime.h>

#define PCEN_EPS 1e-6f

// native clang vector type — required by __builtin_nontemporal_store
typedef float f32x4 __attribute__((ext_vector_type(4)));

// HW transcendentals (v_log_f32 = log2, v_exp_f32 = 2^x, v_sqrt_f32).
// NOTE: do NOT use __log2f/__exp2f — they collide with glibc math.h macros.
#define HW_LOG2(x) __builtin_amdgcn_logf(x)
#define HW_EXP2(x) __builtin_amdgcn_exp2f(x)
#define HW_SQRT(x) __builtin_amdgcn_sqrtf(x)

// One WAVE per (b,c) row, lane-interleaved float4 layout (iteration k, lane i
// covers elements k*256 + 4*i..+3): every wave load/store is a contiguous,
// fully-utilized 1 KB burst.  Uniform-coefficient affine scan per 256-elem
// block, carry chained across iterations by one lane-63 broadcast + fma.
// smooth[0]=x[0] via carry-init = x[0] (a + s == 1).
//
// Round-7 post-mortem: duplicating a FULLY-unrolled 32-step loop (2 x ~20KB)
// blew the 32KB L1I -> I-fetch misses through TCC (FETCH +27MB), issue
// stalls, WRITE amplification. Fix: keep the r==0.5 sqrt fast path and the
// general-r path as two loops, but keep the outer loop ROLLED (unroll 1):
// each body is one 4-step rotation (~2KB), both paths fit L1I trivially.
__global__ __launch_bounds__(256, 8) void pcen_kernel(
    const float* __restrict__ x,
    const float* __restrict__ alpha_p,
    const float* __restrict__ delta_p,
    const float* __restrict__ r_p,
    const float* __restrict__ s_p,
    float* __restrict__ out,
    int C)
{
    constexpr int T  = 8000;
    constexpr int NQ = T / 4;        // 2000 float4 per row

    const int wid  = threadIdx.x >> 6;            // wave in block: 0..3
    const int lane = threadIdx.x & 63;
    const int row  = blockIdx.x * 4 + wid;        // 0 .. B*C-1 (one wave/row)
    const int c    = row % C;

    // per-channel params (clipped like the reference) — wave-uniform
    const float alpha = fminf(fmaxf(alpha_p[c], 0.5f), 1.0f);
    const float delta = fminf(fmaxf(delta_p[c], 0.5f), 10.0f);
    const float r     = fminf(fmaxf(r_p[c],     0.1f), 1.0f);
    const float sq    = fminf(fmaxf(s_p[c],     0.001f), 0.5f);
    const float a     = 1.0f - sq;

    const float dr     = HW_EXP2(r * HW_LOG2(delta));   // delta^r
    const float nalpha = -alpha;

    // powers of a^4 for the uniform-coefficient scan
    const float a4  = (a * a) * (a * a);
    const float p1  = a4;
    const float p2  = p1 * p1;
    const float p4  = p2 * p2;
    const float p8  = p4 * p4;
    const float p16 = p8 * p8;
    const float p32 = p16 * p16;
    const float a256 = p32 * p32;
    const float inv_a4 = 1.0f / a4;

    // masked scan coefficients (lane-dependent, hoisted out of the loop)
    const float m1  = (lane >= 1)  ? p1  : 0.0f;
    const float m2  = (lane >= 2)  ? p2  : 0.0f;
    const float m4  = (lane >= 4)  ? p4  : 0.0f;
    const float m8  = (lane >= 8)  ? p8  : 0.0f;
    const float m16 = (lane >= 16) ? p16 : 0.0f;
    const float m32 = (lane >= 32) ? p32 : 0.0f;

    // Aexc = a4^lane (exclusive-prefix decay for this lane)
    float Aexc = 1.0f;
    if (lane & 1)  Aexc *= p1;
    if (lane & 2)  Aexc *= p2;
    if (lane & 4)  Aexc *= p4;
    if (lane & 8)  Aexc *= p8;
    if (lane & 16) Aexc *= p16;
    if (lane & 32) Aexc *= p32;

    const size_t base = (size_t)row * T;
    const f32x4* __restrict__ xin  = reinterpret_cast<const f32x4*>(x   + base);
    f32x4*       __restrict__ oout = reinterpret_cast<f32x4*>      (out + base);

    // carry init: sm[0] = a*carry + s*x[0] = x[0] when carry = x[0]
    float carry = x[base];

    // ---- 4-deep rotating prefetch pipeline (all prologue idx in range) ----
    int idx = lane;
    f32x4 e0 = xin[idx];
    f32x4 e1 = xin[idx +  64];
    f32x4 e2 = xin[idx + 128];
    f32x4 e3 = xin[idx + 192];

    // per-element tails: smv -> output value
#define PCEN_TAIL_POW(xv, smv, o_)                                           \
    {                                                                        \
        float t_ = HW_EXP2(nalpha * HW_LOG2((smv) + PCEN_EPS));              \
        o_ = HW_EXP2(r * HW_LOG2(fmaf((xv), t_, delta))) - dr;               \
    }
#define PCEN_TAIL_SQRT(xv, smv, o_)                                          \
    {                                                                        \
        float t_ = HW_EXP2(nalpha * HW_LOG2((smv) + PCEN_EPS));              \
        o_ = HW_SQRT(fmaf((xv), t_, delta)) - dr;                            \
    }

    // process one resident quad `eb` at `idx`, prefetch idx+256 into eb
#define PCEN_STEP(eb, TAIL)                                                  \
    {                                                                        \
        const int pidx = idx + 256;                                          \
        f32x4 pf = (f32x4)(0.f);                                             \
        if (pidx < NQ) pf = xin[pidx];                                       \
                                                                             \
        /* hoisted products, shared by affine pass and replay */             \
        const float gx = sq * eb.x, gy = sq * eb.y,                          \
                    gz = sq * eb.z, gw = sq * eb.w;                          \
                                                                             \
        float f = gx;                                                        \
        f = fmaf(a, f, gy);                                                  \
        f = fmaf(a, f, gz);                                                  \
        f = fmaf(a, f, gw);                                                  \
                                                                             \
        /* predicate-free uniform-coefficient scan */                        \
        float fs = f;                                                        \
        fs = fmaf(m1,  __shfl_up(fs, 1,  64), fs);                           \
        fs = fmaf(m2,  __shfl_up(fs, 2,  64), fs);                           \
        fs = fmaf(m4,  __shfl_up(fs, 4,  64), fs);                           \
        fs = fmaf(m8,  __shfl_up(fs, 8,  64), fs);                           \
        fs = fmaf(m16, __shfl_up(fs, 16, 64), fs);                           \
        fs = fmaf(m32, __shfl_up(fs, 32, 64), fs);                           \
                                                                             \
        float fe = (fs - f) * inv_a4;                                        \
        float sm = fmaf(Aexc, carry, fe);                                    \
                                                                             \
        float ftot = __shfl(fs, 63, 64);                                     \
        carry = fmaf(a256, carry, ftot);                                     \
                                                                             \
        f32x4 o;                                                             \
        sm = fmaf(a, sm, gx);  TAIL(eb.x, sm, o.x);                          \
        sm = fmaf(a, sm, gy);  TAIL(eb.y, sm, o.y);                          \
        sm = fmaf(a, sm, gz);  TAIL(eb.z, sm, o.z);                          \
        sm = fmaf(a, sm, gw);  TAIL(eb.w, sm, o.w);                          \
                                                                             \
        if (idx < NQ) __builtin_nontemporal_store(o, oout + idx);            \
        eb = pf;                                                             \
        idx += 64;                                                           \
    }

    // ROLLED outer loop: body = one 4-step rotation (~2KB of code).
#define PCEN_MAIN_LOOP(TAIL)                                                 \
    _Pragma("unroll 1")                                                      \
    for (int k = 0; k < 8; ++k) {   /* 8 x 4 stages = 32 iterations */       \
        PCEN_STEP(e0, TAIL);                                                 \
        PCEN_STEP(e1, TAIL);                                                 \
        PCEN_STEP(e2, TAIL);                                                 \
        PCEN_STEP(e3, TAIL);                                                 \
    }

    if (r == 0.5f) {          // wave-uniform (r is channel-constant)
        PCEN_MAIN_LOOP(PCEN_TAIL_SQRT);
    } else {
        PCEN_MAIN_LOOP(PCEN_TAIL_POW);
    }

#undef PCEN_MAIN_LOOP
#undef PCEN_STEP
#undef PCEN_TAIL_POW
#undef PCEN_TAIL_SQRT
}

extern "C" void kernel_launch(void* const* d_in, const int* in_sizes, int n_in,
                              void* d_out, int out_size, void* d_ws, size_t ws_size,
                              hipStream_t stream) {
    const float* x     = (const float*)d_in[0];
    const float* alpha = (const float*)d_in[1];
    const float* delta = (const float*)d_in[2];
    const float* r     = (const float*)d_in[3];
    const float* s     = (const float*)d_in[4];
    float* out = (float*)d_out;

    const int T = 8000;                    // fixed by the reference problem
    const int C = in_sizes[1];             // 128
    const int rows = in_sizes[0] / T;      // B*C = 8192

    pcen_kernel<<<rows / 4, 256, 0, stream>>>(x, alpha, delta, r, s, out, C);
}

// Round 9
// 92.762 us; speedup vs baseline: 1.2286x; 1.2237x over previous
//
#include <hip/hip_runtime.h>

#define PCEN_EPS 1e-6f

// native clang vector type — required by __builtin_nontemporal_store
typedef float f32x4 __attribute__((ext_vector_type(4)));

// HW transcendentals (v_log_f32 = log2, v_exp_f32 = 2^x).
// NOTE: do NOT use __log2f/__exp2f — they collide with glibc math.h macros.
#define HW_LOG2(x) __builtin_amdgcn_logf(x)
#define HW_EXP2(x) __builtin_amdgcn_exp2f(x)

// One WAVE per (b,c) row, lane-interleaved float4 layout (iteration k, lane i
// covers elements k*256 + 4*i..+3): every wave load/store is a contiguous,
// fully-utilized 1 KB burst.  Uniform-coefficient affine scan per 256-elem
// block, carry chained across iterations by one lane-63 broadcast + fma.
// smooth[0]=x[0] via carry-init = x[0] (a + s == 1).
//
// BISECTION ROUND (R5=88.8us vs R7/R8=113.5us mystery): this is EXACTLY the
// R5 structure — single pow path, NO r==0.5 branch, full unroll, temporal
// loads, nt stores, 4-deep static prefetch — with only the intra-loop
// micro-opts from R7/R8 applied: HW log2/exp2 (no ln2-fixup muls), masked
// predicate-free scan, hoisted sq*e products. If this holds ~85us the
// two-loop branch was the poison; if it regresses to ~113 these opts are.
__global__ __launch_bounds__(256, 8) void pcen_kernel(
    const float* __restrict__ x,
    const float* __restrict__ alpha_p,
    const float* __restrict__ delta_p,
    const float* __restrict__ r_p,
    const float* __restrict__ s_p,
    float* __restrict__ out,
    int C)
{
    constexpr int T  = 8000;
    constexpr int NQ = T / 4;        // 2000 float4 per row

    const int wid  = threadIdx.x >> 6;            // wave in block: 0..3
    const int lane = threadIdx.x & 63;
    const int row  = blockIdx.x * 4 + wid;        // 0 .. B*C-1 (one wave/row)
    const int c    = row % C;

    // per-channel params (clipped like the reference) — wave-uniform
    const float alpha = fminf(fmaxf(alpha_p[c], 0.5f), 1.0f);
    const float delta = fminf(fmaxf(delta_p[c], 0.5f), 10.0f);
    const float r     = fminf(fmaxf(r_p[c],     0.1f), 1.0f);
    const float sq    = fminf(fmaxf(s_p[c],     0.001f), 0.5f);
    const float a     = 1.0f - sq;

    const float dr     = HW_EXP2(r * HW_LOG2(delta));   // delta^r
    const float nalpha = -alpha;

    // powers of a^4 for the uniform-coefficient scan
    const float a4  = (a * a) * (a * a);
    const float p1  = a4;
    const float p2  = p1 * p1;
    const float p4  = p2 * p2;
    const float p8  = p4 * p4;
    const float p16 = p8 * p8;
    const float p32 = p16 * p16;
    const float a256 = p32 * p32;
    const float inv_a4 = 1.0f / a4;

    // masked scan coefficients (lane-dependent, hoisted out of the loop)
    const float m1  = (lane >= 1)  ? p1  : 0.0f;
    const float m2  = (lane >= 2)  ? p2  : 0.0f;
    const float m4  = (lane >= 4)  ? p4  : 0.0f;
    const float m8  = (lane >= 8)  ? p8  : 0.0f;
    const float m16 = (lane >= 16) ? p16 : 0.0f;
    const float m32 = (lane >= 32) ? p32 : 0.0f;

    // Aexc = a4^lane (exclusive-prefix decay for this lane)
    float Aexc = 1.0f;
    if (lane & 1)  Aexc *= p1;
    if (lane & 2)  Aexc *= p2;
    if (lane & 4)  Aexc *= p4;
    if (lane & 8)  Aexc *= p8;
    if (lane & 16) Aexc *= p16;
    if (lane & 32) Aexc *= p32;

    const size_t base = (size_t)row * T;
    const f32x4* __restrict__ xin  = reinterpret_cast<const f32x4*>(x   + base);
    f32x4*       __restrict__ oout = reinterpret_cast<f32x4*>      (out + base);

    // carry init: sm[0] = a*carry + s*x[0] = x[0] when carry = x[0]
    float carry = x[base];

    // ---- 4-deep rotating prefetch pipeline (all prologue idx in range) ----
    int idx = lane;
    f32x4 e0 = xin[idx];
    f32x4 e1 = xin[idx +  64];
    f32x4 e2 = xin[idx + 128];
    f32x4 e3 = xin[idx + 192];

    // general-r tail: 4 transcendentals, no libm fixup muls
#define PCEN_TAIL(xv, smv, o_)                                               \
    {                                                                        \
        float t_ = HW_EXP2(nalpha * HW_LOG2((smv) + PCEN_EPS));              \
        o_ = HW_EXP2(r * HW_LOG2(fmaf((xv), t_, delta))) - dr;               \
    }

    // process one resident quad `eb` at `idx`, prefetch idx+256 into eb
#define PCEN_STEP(eb)                                                        \
    {                                                                        \
        const int pidx = idx + 256;                                          \
        f32x4 pf = (f32x4)(0.f);                                             \
        if (pidx < NQ) pf = xin[pidx];                                       \
                                                                             \
        /* hoisted products, shared by affine pass and replay */             \
        const float gx = sq * eb.x, gy = sq * eb.y,                          \
                    gz = sq * eb.z, gw = sq * eb.w;                          \
                                                                             \
        float f = gx;                                                        \
        f = fmaf(a, f, gy);                                                  \
        f = fmaf(a, f, gz);                                                  \
        f = fmaf(a, f, gw);                                                  \
                                                                             \
        /* predicate-free uniform-coefficient scan */                        \
        float fs = f;                                                        \
        fs = fmaf(m1,  __shfl_up(fs, 1,  64), fs);                           \
        fs = fmaf(m2,  __shfl_up(fs, 2,  64), fs);                           \
        fs = fmaf(m4,  __shfl_up(fs, 4,  64), fs);                           \
        fs = fmaf(m8,  __shfl_up(fs, 8,  64), fs);                           \
        fs = fmaf(m16, __shfl_up(fs, 16, 64), fs);                           \
        fs = fmaf(m32, __shfl_up(fs, 32, 64), fs);                           \
                                                                             \
        float fe = (fs - f) * inv_a4;                                        \
        float sm = fmaf(Aexc, carry, fe);                                    \
                                                                             \
        float ftot = __shfl(fs, 63, 64);                                     \
        carry = fmaf(a256, carry, ftot);                                     \
                                                                             \
        f32x4 o;                                                             \
        sm = fmaf(a, sm, gx);  PCEN_TAIL(eb.x, sm, o.x);                     \
        sm = fmaf(a, sm, gy);  PCEN_TAIL(eb.y, sm, o.y);                     \
        sm = fmaf(a, sm, gz);  PCEN_TAIL(eb.z, sm, o.z);                     \
        sm = fmaf(a, sm, gw);  PCEN_TAIL(eb.w, sm, o.w);                     \
                                                                             \
        if (idx < NQ) __builtin_nontemporal_store(o, oout + idx);            \
        eb = pf;                                                             \
        idx += 64;                                                           \
    }

    #pragma unroll
    for (int k = 0; k < 8; ++k) {   // 8 x 4 stages = 32 iterations
        PCEN_STEP(e0);
        PCEN_STEP(e1);
        PCEN_STEP(e2);
        PCEN_STEP(e3);
    }
#undef PCEN_STEP
#undef PCEN_TAIL
}

extern "C" void kernel_launch(void* const* d_in, const int* in_sizes, int n_in,
                              void* d_out, int out_size, void* d_ws, size_t ws_size,
                              hipStream_t stream) {
    const float* x     = (const float*)d_in[0];
    const float* alpha = (const float*)d_in[1];
    const float* delta = (const float*)d_in[2];
    const float* r     = (const float*)d_in[3];
    const float* s     = (const float*)d_in[4];
    float* out = (float*)d_out;

    const int T = 8000;                    // fixed by the reference problem
    const int C = in_sizes[1];             // 128
    const int rows = in_sizes[0] / T;      // B*C = 8192

    pcen_kernel<<<rows / 4, 256, 0, stream>>>(x, alpha, delta, r, s, out, C);
}

// Round 10
// 89.492 us; speedup vs baseline: 1.2735x; 1.0365x over previous
//
#include <hip/hip_runtime.h>

#define PCEN_EPS 1e-6f

// native clang vector type — required by __builtin_nontemporal_store
typedef float f32x4 __attribute__((ext_vector_type(4)));

// HW transcendentals (v_log_f32 = log2, v_exp_f32 = 2^x).
// NOTE: do NOT use __log2f/__exp2f — they collide with glibc math.h macros.
#define HW_LOG2(x) __builtin_amdgcn_logf(x)
#define HW_EXP2(x) __builtin_amdgcn_exp2f(x)

// One WAVE per (b,c) row, lane-interleaved float4 layout.  Uniform-coefficient
// affine scan per 256-elem block; smooth[0]=x[0] via carry-init = x[0].
//
// R9 post-mortem: traffic minimal (128/256 MB) but dur 92.8us >> 61us byte
// floor, VALUBusy 20%, BW 60% of fill-rate -> serialization-bound on the
// per-iteration 7-shuffle carry chain.  This rev: PAIRWISE-BATCHED scans —
// two independent 256-elem blocks scanned with their shuffle chains
// interleaved (latency overlap), carry composed afterwards with 2 fma.
// Serial chain per 512 elems ~halves; memory ops issue 2-at-a-time.
// Single path, no r-branch (R7/R8 poison), full unroll, temporal loads,
// nt stores, rotation keeps <=6 quads live (VGPR<=64 -> 32 waves/CU).
__global__ __launch_bounds__(256, 8) void pcen_kernel(
    const float* __restrict__ x,
    const float* __restrict__ alpha_p,
    const float* __restrict__ delta_p,
    const float* __restrict__ r_p,
    const float* __restrict__ s_p,
    float* __restrict__ out,
    int C)
{
    constexpr int T  = 8000;
    constexpr int NQ = T / 4;        // 2000 float4 per row

    const int wid  = threadIdx.x >> 6;            // wave in block: 0..3
    const int lane = threadIdx.x & 63;
    const int row  = blockIdx.x * 4 + wid;        // 0 .. B*C-1 (one wave/row)
    const int c    = row % C;

    // per-channel params (clipped like the reference) — wave-uniform
    const float alpha = fminf(fmaxf(alpha_p[c], 0.5f), 1.0f);
    const float delta = fminf(fmaxf(delta_p[c], 0.5f), 10.0f);
    const float r     = fminf(fmaxf(r_p[c],     0.1f), 1.0f);
    const float sq    = fminf(fmaxf(s_p[c],     0.001f), 0.5f);
    const float a     = 1.0f - sq;

    const float dr     = HW_EXP2(r * HW_LOG2(delta));   // delta^r
    const float nalpha = -alpha;

    // powers of a^4 for the uniform-coefficient scan
    const float a4  = (a * a) * (a * a);
    const float p1  = a4;
    const float p2  = p1 * p1;
    const float p4  = p2 * p2;
    const float p8  = p4 * p4;
    const float p16 = p8 * p8;
    const float p32 = p16 * p16;
    const float a256 = p32 * p32;
    const float inv_a4 = 1.0f / a4;

    // masked scan coefficients (lane-dependent, hoisted out of the loop)
    const float m1  = (lane >= 1)  ? p1  : 0.0f;
    const float m2  = (lane >= 2)  ? p2  : 0.0f;
    const float m4  = (lane >= 4)  ? p4  : 0.0f;
    const float m8  = (lane >= 8)  ? p8  : 0.0f;
    const float m16 = (lane >= 16) ? p16 : 0.0f;
    const float m32 = (lane >= 32) ? p32 : 0.0f;

    // Aexc = a4^lane (exclusive-prefix decay for this lane)
    float Aexc = 1.0f;
    if (lane & 1)  Aexc *= p1;
    if (lane & 2)  Aexc *= p2;
    if (lane & 4)  Aexc *= p4;
    if (lane & 8)  Aexc *= p8;
    if (lane & 16) Aexc *= p16;
    if (lane & 32) Aexc *= p32;

    const size_t base = (size_t)row * T;
    const f32x4* __restrict__ xin  = reinterpret_cast<const f32x4*>(x   + base);
    f32x4*       __restrict__ oout = reinterpret_cast<f32x4*>      (out + base);

    // carry init: sm[0] = a*carry + s*x[0] = x[0] when carry = x[0]
    float carry = x[base];

    // ---- 4-slot rotation, all prologue idx in range ----
    int idx = lane;
    f32x4 e0 = xin[idx];
    f32x4 e1 = xin[idx +  64];
    f32x4 e2 = xin[idx + 128];
    f32x4 e3 = xin[idx + 192];

    // general-r tail: 4 transcendentals, no libm fixup muls
#define PCEN_TAIL(xv, smv, o_)                                               \
    {                                                                        \
        float t_ = HW_EXP2(nalpha * HW_LOG2((smv) + PCEN_EPS));              \
        o_ = HW_EXP2(r * HW_LOG2(fmaf((xv), t_, delta))) - dr;               \
    }

    // Process blocks eA (quads @idx) and eB (@idx+64) together; prefetch
    // @idx+256 and @idx+320 into the consumed slots; advance idx by 128.
#define PCEN_PAIR(eA, eB)                                                    \
    {                                                                        \
        const int pA = idx + 256, pB = idx + 320;                            \
        f32x4 lA = (f32x4)(0.f), lB = (f32x4)(0.f);                          \
        if (pA < NQ) lA = xin[pA];                                           \
        if (pB < NQ) lB = xin[pB];                                           \
                                                                             \
        /* per-lane affine offsets for both blocks */                        \
        float fA = sq * eA.x;                                                \
        fA = fmaf(a, fA, sq * eA.y);                                         \
        fA = fmaf(a, fA, sq * eA.z);                                         \
        fA = fmaf(a, fA, sq * eA.w);                                         \
        float fB = sq * eB.x;                                                \
        fB = fmaf(a, fB, sq * eB.y);                                         \
        fB = fmaf(a, fB, sq * eB.z);                                         \
        fB = fmaf(a, fB, sq * eB.w);                                         \
                                                                             \
        /* two INDEPENDENT scans, shuffle chains interleaved */              \
        float sA = fA, sB = fB, tA, tB;                                      \
        tA = __shfl_up(sA, 1,  64);  tB = __shfl_up(sB, 1,  64);             \
        sA = fmaf(m1,  tA, sA);      sB = fmaf(m1,  tB, sB);                 \
        tA = __shfl_up(sA, 2,  64);  tB = __shfl_up(sB, 2,  64);             \
        sA = fmaf(m2,  tA, sA);      sB = fmaf(m2,  tB, sB);                 \
        tA = __shfl_up(sA, 4,  64);  tB = __shfl_up(sB, 4,  64);             \
        sA = fmaf(m4,  tA, sA);      sB = fmaf(m4,  tB, sB);                 \
        tA = __shfl_up(sA, 8,  64);  tB = __shfl_up(sB, 8,  64);             \
        sA = fmaf(m8,  tA, sA);      sB = fmaf(m8,  tB, sB);                 \
        tA = __shfl_up(sA, 16, 64);  tB = __shfl_up(sB, 16, 64);             \
        sA = fmaf(m16, tA, sA);      sB = fmaf(m16, tB, sB);                 \
        tA = __shfl_up(sA, 32, 64);  tB = __shfl_up(sB, 32, 64);             \
        sA = fmaf(m32, tA, sA);      sB = fmaf(m32, tB, sB);                 \
                                                                             \
        /* cross-block carry composition (2 fma after both scans) */         \
        const float ftA = __shfl(sA, 63, 64);                                \
        const float ftB = __shfl(sB, 63, 64);                                \
        const float cA  = carry;                                             \
        const float cB  = fmaf(a256, cA, ftA);                               \
        carry = fmaf(a256, cB, ftB);                                         \
                                                                             \
        /* smoother entering each lane, replay + pcen tails, stores */       \
        float smA = fmaf(Aexc, cA, (sA - fA) * inv_a4);                      \
        float smB = fmaf(Aexc, cB, (sB - fB) * inv_a4);                      \
        f32x4 oA, oB;                                                        \
        smA = fmaf(a, smA, sq * eA.x);  PCEN_TAIL(eA.x, smA, oA.x);          \
        smA = fmaf(a, smA, sq * eA.y);  PCEN_TAIL(eA.y, smA, oA.y);          \
        smA = fmaf(a, smA, sq * eA.z);  PCEN_TAIL(eA.z, smA, oA.z);          \
        smA = fmaf(a, smA, sq * eA.w);  PCEN_TAIL(eA.w, smA, oA.w);          \
        smB = fmaf(a, smB, sq * eB.x);  PCEN_TAIL(eB.x, smB, oB.x);          \
        smB = fmaf(a, smB, sq * eB.y);  PCEN_TAIL(eB.y, smB, oB.y);          \
        smB = fmaf(a, smB, sq * eB.z);  PCEN_TAIL(eB.z, smB, oB.z);          \
        smB = fmaf(a, smB, sq * eB.w);  PCEN_TAIL(eB.w, smB, oB.w);          \
                                                                             \
        if (idx      < NQ) __builtin_nontemporal_store(oA, oout + idx);      \
        if (idx + 64 < NQ) __builtin_nontemporal_store(oB, oout + idx + 64); \
                                                                             \
        eA = lA;                                                             \
        eB = lB;                                                             \
        idx += 128;                                                         \
    }

    #pragma unroll
    for (int g = 0; g < 8; ++g) {   // 8 x 2 pairs = 16 pairs = 2048 quads
        PCEN_PAIR(e0, e1);
        PCEN_PAIR(e2, e3);
    }
#undef PCEN_PAIR
#undef PCEN_TAIL
}

extern "C" void kernel_launch(void* const* d_in, const int* in_sizes, int n_in,
                              void* d_out, int out_size, void* d_ws, size_t ws_size,
                              hipStream_t stream) {
    const float* x     = (const float*)d_in[0];
    const float* alpha = (const float*)d_in[1];
    const float* delta = (const float*)d_in[2];
    const float* r     = (const float*)d_in[3];
    const float* s     = (const float*)d_in[4];
    float* out = (float*)d_out;

    const int T = 8000;                    // fixed by the reference problem
    const int C = in_sizes[1];             // 128
    const int rows = in_sizes[0] / T;      // B*C = 8192

    pcen_kernel<<<rows / 4, 256, 0, stream>>>(x, alpha, delta, r, s, out, C);
}